// Round 3
// baseline (297.349 us; speedup 1.0000x reference)
//
#include <hip/hip_runtime.h>
#include <math.h>

// MelGaussianFilteredMSE:
//   diff = 10^(mo/10) - 10^(tg/10)            (B=32, F=1025, T=2000, fp32)
//   out  = mean( (M @ diff along F)^2 )       M is BANDED: half-width <= 10
//
// R2: streaming register rolling-window FIR.
//  - coeff band read from LDS as 6x ds_read_b128 per output row (was 21x b32
//    broadcast -> LDS issue pipe was the R1 bottleneck)
//  - fast path for interior f-chunks: incremental pointers, no clamp/mask
//  - __launch_bounds__(256,5) for 5 blocks/CU

#define B_N 32
#define F_N 1025
#define T_N 2000

#define NOUT   64    // output rows per f-chunk
#define ROWS   84    // NOUT + 20 halo = 4*21 (static window slots)
#define NCHUNK 17    // 17*64 = 1088 >= 1025
#define NT     256   // threads per block
#define CT     512   // t-columns per block (256 threads * 2)
#define CST    24    // coeff LDS row stride (21 padded to 24 floats, 96 B)

#define LOG2_10_DIV10 0.33219280948873623f   // 10^(x/10) = 2^(x*this)

__global__ __launch_bounds__(NT, 5)
void mel_mse_stream(const float* __restrict__ mo_g, const float* __restrict__ tg_g,
                    const float* __restrict__ M, float* __restrict__ partials) {
    __shared__ float sm[NOUT * CST];   // 64*24*4 = 6144 B
    __shared__ float red[NT];          //           1024 B

    const int tid = threadIdx.x;
    const int t0  = blockIdx.x * CT;
    const int f0  = blockIdx.y * NOUT;
    const int b   = blockIdx.z;
    const int t   = t0 + tid * 2;
    const bool active = (t + 1 < T_N);       // T_N even: both cols valid or neither
    const int base = f0 - 10;                // global row of stream step 0

    // ---- stage the 21-wide coefficient band (zero-padded to CST) ----
    for (int i = tid; i < NOUT * CST; i += NT) {
        const int row = i / CST;
        const int j   = i - row * CST;
        const int f   = f0 + row;
        const int k   = f - 10 + j;
        float v = 0.f;
        if (j < 21 && f < F_N && k >= 0 && k < F_N) v = M[(size_t)f * F_N + k];
        sm[i] = v;
    }
    __syncthreads();

    const int tc = active ? t : 0;

    float2 w[21];                            // rolling window, static-indexed only
    float2 acc = make_float2(0.f, 0.f);

    // coeff row -> registers via 6x b128, then 21 FMAs against the window
    auto OUTF = [&](int r_out, const int s0) {
        float cf[24];
        const float4* c4 = reinterpret_cast<const float4*>(&sm[r_out * CST]);
#pragma unroll
        for (int q = 0; q < 6; ++q)
            *reinterpret_cast<float4*>(&cf[q * 4]) = c4[q];
        float2 o = make_float2(0.f, 0.f);
#pragma unroll
        for (int j = 0; j < 21; ++j) {
            const float2 wv = w[(s0 + j) % 21];
            o.x = fmaf(cf[j], wv.x, o.x);
            o.y = fmaf(cf[j], wv.y, o.y);
        }
        acc.x = fmaf(o.x, o.x, acc.x);
        acc.y = fmaf(o.y, o.y, acc.y);
    };

    const bool fast = (base >= 0) && (base + ROWS <= F_N);   // uniform per block

    if (fast) {
        const float* pm = mo_g + ((size_t)b * F_N + base) * (size_t)T_N + tc;
        const float* pt = tg_g + ((size_t)b * F_N + base) * (size_t)T_N + tc;
        auto LOADF = [&]() -> float2 {
            const float2 a = *reinterpret_cast<const float2*>(pm);
            const float2 c = *reinterpret_cast<const float2*>(pt);
            pm += T_N; pt += T_N;
            float2 d;
            d.x = exp2f(a.x * LOG2_10_DIV10) - exp2f(c.x * LOG2_10_DIV10);
            d.y = exp2f(a.y * LOG2_10_DIV10) - exp2f(c.y * LOG2_10_DIV10);
            return d;
        };
#pragma unroll
        for (int i = 0; i < 21; ++i) w[i] = LOADF();
        OUTF(0, 0);
        for (int m = 1; m < 4; ++m) {
            const int rb = m * 21;
#pragma unroll
            for (int i = 0; i < 21; ++i) {
                w[i] = LOADF();                  // stream row rb+i -> slot i
                OUTF(rb + i - 20, (i + 1) % 21); // static slot base
            }
        }
    } else {
        const size_t colbase = ((size_t)b * F_N) * (size_t)T_N + tc;
        auto LOADS = [&](int r) -> float2 {
            int g = base + r;
            const float mask = (g >= 0 && g < F_N) ? 1.f : 0.f;
            g = g < 0 ? 0 : (g >= F_N ? F_N - 1 : g);
            const size_t off = colbase + (size_t)g * T_N;
            const float2 a = *reinterpret_cast<const float2*>(mo_g + off);
            const float2 c = *reinterpret_cast<const float2*>(tg_g + off);
            float2 d;
            d.x = (exp2f(a.x * LOG2_10_DIV10) - exp2f(c.x * LOG2_10_DIV10)) * mask;
            d.y = (exp2f(a.y * LOG2_10_DIV10) - exp2f(c.y * LOG2_10_DIV10)) * mask;
            return d;
        };
        auto OUTS = [&](int r_out, const int s0) {
            if (f0 + r_out < F_N) OUTF(r_out, s0);
        };
#pragma unroll
        for (int i = 0; i < 21; ++i) w[i] = LOADS(i);
        OUTS(0, 0);
        for (int m = 1; m < 4; ++m) {
            const int rb = m * 21;
#pragma unroll
            for (int i = 0; i < 21; ++i) {
                w[i] = LOADS(rb + i);
                OUTS(rb + i - 20, (i + 1) % 21);
            }
        }
    }

    if (!active) acc = make_float2(0.f, 0.f);

    // ---- block reduction ----
    red[tid] = acc.x + acc.y;
    __syncthreads();
    for (int s = NT / 2; s > 0; s >>= 1) {
        if (tid < s) red[tid] += red[tid + s];
        __syncthreads();
    }
    if (tid == 0) {
        const int bid = blockIdx.x + gridDim.x * (blockIdx.y + gridDim.y * blockIdx.z);
        partials[bid] = red[0];
    }
}

__global__ void mel_mse_reduce(const float* __restrict__ partials, int n,
                               float* __restrict__ out) {
    __shared__ double red[256];
    double s = 0.0;
    for (int i = threadIdx.x; i < n; i += 256) s += (double)partials[i];
    red[threadIdx.x] = s;
    __syncthreads();
    for (int st = 128; st > 0; st >>= 1) {
        if (threadIdx.x < st) red[threadIdx.x] += red[threadIdx.x + st];
        __syncthreads();
    }
    if (threadIdx.x == 0)
        out[0] = (float)(red[0] / (double)((long long)B_N * F_N * T_N));
}

extern "C" void kernel_launch(void* const* d_in, const int* in_sizes, int n_in,
                              void* d_out, int out_size, void* d_ws, size_t ws_size,
                              hipStream_t stream) {
    const float* mo = (const float*)d_in[0];   // model_output (32,1025,2000) fp32
    const float* tg = (const float*)d_in[1];   // target       (32,1025,2000) fp32
    const float* M  = (const float*)d_in[2];   // transform_matrix (1025,1025) fp32
    float* out      = (float*)d_out;           // scalar fp32
    float* partials = (float*)d_ws;            // 4*17*32*4 = 8704 B of d_ws

    dim3 grid((T_N + CT - 1) / CT,             // 4 t-tiles
              NCHUNK,                          // 17 f-chunks
              B_N);                            // 32 batches
    const int nparts = grid.x * grid.y * grid.z;

    mel_mse_stream<<<grid, NT, 0, stream>>>(mo, tg, M, partials);
    mel_mse_reduce<<<1, 256, 0, stream>>>(partials, nparts, out);
}

// Round 4
// 195.134 us; speedup vs baseline: 1.5238x; 1.5238x over previous
//
#include <hip/hip_runtime.h>
#include <math.h>

// MelGaussianFilteredMSE:
//   diff = 10^(mo/10) - 10^(tg/10)            (B=32, F=1025, T=2000, fp32)
//   out  = mean( (M @ diff along F)^2 )       M is BANDED: half-width <= 10
//
// R3: latency-bound fix. Streaming register FIR with:
//  - raw-load prefetch ring of 7 rows (loads issue 7 iterations before the
//    exp2+FIR consume -> 14 loads in flight/thread instead of ~2)
//  - coefficient band pre-packed (setup kernel) into aligned 24-float rows in
//    d_ws; read with wave-uniform float4 loads -> s_load into SGPRs; FMAs use
//    the 1-SGPR-operand form. NO LDS in the main loop.
//  - 1 t-column/thread, __launch_bounds__(256,8) for 8 waves/SIMD
//  - single unified masked path (row mask = SGPR multiplier; column mask
//    folded into acc once at the end)

#define B_N 32
#define F_N 1025
#define T_N 2000

#define NOUT   106                 // output rows per f-chunk
#define ROWS   126                 // NOUT + 20 halo = 6*21
#define NCHUNK 10
#define NT     256                 // threads per block = t-columns per block
#define PF     7                   // prefetch ring depth (lcm(7,21)=21 -> static slots)
#define CBS    24                  // band row stride in floats (96 B, 16B-aligned)
#define BANDROWS (NCHUNK * NOUT)   // 1060 rows (rows >= 1025 are zeros)

#define LOG2_10_DIV10 0.33219280948873623f   // 10^(x/10) = 2^(x*this)

__global__ void build_band(const float* __restrict__ M, float* __restrict__ band) {
    const int idx = blockIdx.x * 256 + threadIdx.x;
    if (idx >= BANDROWS * CBS) return;
    const int f = idx / CBS;
    const int j = idx - f * CBS;
    const int k = f - 10 + j;
    float v = 0.f;
    if (j < 21 && f < F_N && k >= 0 && k < F_N) v = M[(size_t)f * F_N + k];
    band[idx] = v;
}

__global__ __launch_bounds__(NT, 8)
void mel_mse_stream(const float* __restrict__ mo_g, const float* __restrict__ tg_g,
                    const float* __restrict__ band, float* __restrict__ partials) {
    __shared__ float red[NT];

    const int tid  = threadIdx.x;
    const int t    = blockIdx.x * NT + tid;
    const int f0   = blockIdx.y * NOUT;
    const int b    = blockIdx.z;
    const int base = f0 - 10;                 // global input row of stream step 0

    const bool colv  = (t < T_N);
    const int  tc    = colv ? t : 0;
    const float cmask = colv ? 1.f : 0.f;     // folded into acc at the end

    float w[21];                              // diff window (static-indexed)
    float ra[PF], rc[PF];                     // raw prefetch rings
    float rm[PF];                             // row-valid mask ring (uniform -> SGPRs)
    float acc = 0.f;

    // issue loads for stream row n into ring slot s (addresses uniform-base + tc)
    auto ISSUE = [&](int n, int s) {
        const int g  = base + n;
        rm[s] = (g >= 0 && g < F_N) ? 1.f : 0.f;             // uniform
        const int gc = g < 0 ? 0 : (g > F_N - 1 ? F_N - 1 : g);
        const size_t off = ((size_t)b * F_N + gc) * (size_t)T_N + tc;
        ra[s] = mo_g[off];
        rc[s] = tg_g[off];
    };
    // consume ring slot s -> diff -> window slot ws
    auto CONSUME = [&](int s, int ws) {
        const float d = (exp2f(ra[s] * LOG2_10_DIV10) -
                         exp2f(rc[s] * LOG2_10_DIV10)) * rm[s];
        w[ws] = d;
    };
    // emit output row frow (global); s0 = window slot of tap 0 (compile-time)
    auto OUT = [&](int frow, int s0) {
        float cf[24];                                          // uniform -> SGPRs
        const float4* c4 = reinterpret_cast<const float4*>(band + (size_t)frow * CBS);
#pragma unroll
        for (int q = 0; q < 6; ++q)
            *reinterpret_cast<float4*>(&cf[q * 4]) = c4[q];
        float o = 0.f;
#pragma unroll
        for (int j = 0; j < 21; ++j)
            o = fmaf(cf[j], w[(s0 + j) % 21], o);              // v_fmac v,s,v
        acc = fmaf(o, o, acc);
    };

    // ---- prologue: issue rows 0..6 ----
#pragma unroll
    for (int i = 0; i < PF; ++i) ISSUE(i, i);

    // ---- macro 0 (rows 0..20): fill window, first output at n=20 ----
#pragma unroll
    for (int i = 0; i < 21; ++i) {
        CONSUME(i % PF, i);
        ISSUE(i + PF, i % PF);                 // rows 7..27
        if (i == 20) OUT(f0, 0);
    }
    // ---- macros 1..4 (rows 21..104), output every row ----
    for (int m = 1; m < 5; ++m) {
        const int nb = m * 21;
#pragma unroll
        for (int i = 0; i < 21; ++i) {
            CONSUME(i % PF, i);
            ISSUE(nb + i + PF, i % PF);        // rows nb+7 .. nb+27
            OUT(f0 + nb + i - 20, (i + 1) % 21);
        }
    }
    // ---- macro 5 (rows 105..125): drain; issue only rows 112..125 ----
#pragma unroll
    for (int i = 0; i < 21; ++i) {
        CONSUME(i % PF, i);
        if (i < ROWS - 105 - PF)               // i < 14
            ISSUE(105 + i + PF, i % PF);
        OUT(f0 + 105 + i - 20, (i + 1) % 21);
    }

    acc *= cmask;

    // ---- block reduction ----
    red[tid] = acc;
    __syncthreads();
    for (int s = NT / 2; s > 0; s >>= 1) {
        if (tid < s) red[tid] += red[tid + s];
        __syncthreads();
    }
    if (tid == 0) {
        const int bid = blockIdx.x + gridDim.x * (blockIdx.y + gridDim.y * blockIdx.z);
        partials[bid] = red[0];
    }
}

__global__ void mel_mse_reduce(const float* __restrict__ partials, int n,
                               float* __restrict__ out) {
    __shared__ double red[256];
    double s = 0.0;
    for (int i = threadIdx.x; i < n; i += 256) s += (double)partials[i];
    red[threadIdx.x] = s;
    __syncthreads();
    for (int st = 128; st > 0; st >>= 1) {
        if (threadIdx.x < st) red[threadIdx.x] += red[threadIdx.x + st];
        __syncthreads();
    }
    if (threadIdx.x == 0)
        out[0] = (float)(red[0] / (double)((long long)B_N * F_N * T_N));
}

extern "C" void kernel_launch(void* const* d_in, const int* in_sizes, int n_in,
                              void* d_out, int out_size, void* d_ws, size_t ws_size,
                              hipStream_t stream) {
    const float* mo = (const float*)d_in[0];   // model_output (32,1025,2000) fp32
    const float* tg = (const float*)d_in[1];   // target       (32,1025,2000) fp32
    const float* M  = (const float*)d_in[2];   // transform_matrix (1025,1025) fp32

    float* out  = (float*)d_out;
    float* band = (float*)d_ws;                              // 1060*24*4 = 101760 B
    float* partials = (float*)((char*)d_ws + 102400);        // 2560*4    = 10240 B

    // pack the 21-wide band into aligned 24-float rows (rows >= 1025 zero)
    build_band<<<(BANDROWS * CBS + 255) / 256, 256, 0, stream>>>(M, band);

    dim3 grid((T_N + NT - 1) / NT,             // 8 t-tiles (2048 cols, tail masked)
              NCHUNK,                          // 10 f-chunks
              B_N);                            // 32 batches
    const int nparts = grid.x * grid.y * grid.z;   // 2560

    mel_mse_stream<<<grid, NT, 0, stream>>>(mo, tg, band, partials);
    mel_mse_reduce<<<1, 256, 0, stream>>>(partials, nparts, out);
}